// Round 5
// baseline (326.706 us; speedup 1.0000x reference)
//
#include <hip/hip_runtime.h>
#include <hip/hip_bf16.h>
#include <math.h>

#define EPS_LN 1e-5f
#define EPS_W  1e-16f
#define STAGE_N 1280        // float4 slots staged in LDS per block (20 KB)
#define STAGE_LIM 320       // max chunk per wave (STAGE_N/4)

__device__ __forceinline__ float cvt(const __hip_bfloat16 v) { return __bfloat162float(v); }
__device__ __forceinline__ float cvt(const float v)          { return v; }

// Branchy top-3 insert on packed u64 keys -- merge phases only (few elems).
__device__ __forceinline__ void ins3k(unsigned long long nk,
                                      unsigned long long& B0,
                                      unsigned long long& B1,
                                      unsigned long long& B2) {
    if (nk < B2) {
        if (nk < B1) {
            B2 = B1;
            if (nk < B0) { B1 = B0; B0 = nk; } else B1 = nk;
        } else B2 = nk;
    }
}

// Stage positions -> fp32 float4 (x, y, z, |p|^2) + bf16/fp32 dtype detection.
__global__ __launch_bounds__(256)
void stage_kernel(const void* pmesh, int Nm, const void* ppiv, int Np,
                  float4* __restrict__ mesh_s, float4* __restrict__ piv_s,
                  int* __restrict__ flag) {
    __shared__ int sbad;
    if (threadIdx.x == 0) sbad = 0;
    __syncthreads();
    {
        const __hip_bfloat16* pb = (const __hip_bfloat16*)ppiv;
        int bad = 0;
        for (int i = threadIdx.x; i < Np * 3; i += 256) {
            float v = __bfloat162float(pb[i]);
            if (!(v >= 0.0f && v <= 1.0f)) bad = 1;   // NaN lands here too
        }
        if (bad) sbad = 1;   // benign race
    }
    __syncthreads();
    const int isf32 = sbad;

    int gid = blockIdx.x * 256 + threadIdx.x;
    if (gid == 0) *flag = isf32;
    const int total = Nm + Np;
    if (gid >= total) return;
    const int isMesh = gid < Nm ? 1 : 0;
    const int idx = isMesh ? gid : gid - Nm;
    const void* src = isMesh ? pmesh : ppiv;
    float x, y, z;
    if (isf32) {
        const float* p = (const float*)src;
        x = p[idx*3+0]; y = p[idx*3+1]; z = p[idx*3+2];
    } else {
        const __hip_bfloat16* p = (const __hip_bfloat16*)src;
        x = cvt(p[idx*3+0]); y = cvt(p[idx*3+1]); z = cvt(p[idx*3+2]);
    }
    float4 o; o.x = x; o.y = y; o.z = z; o.w = x*x + y*y + z*z;
    (isMesh ? mesh_s : piv_s)[idx] = o;
}

// kNN scan: LDS-staged candidates, one LANE per query, BRANCHLESS top-3.
// Key = (monotone(dist_bits) << 32) | candidate_index; u64 ascending order
// == (distance asc, index asc) -- exactly jax.lax.top_k's stable tie order.
// 5 u64 min/max network per candidate, no loop-carried branches.
__global__ __launch_bounds__(256)
void knn_scan_kernel(const float4* __restrict__ cand, int Nc,
                     const float4* __restrict__ qry, int Nq,
                     int nslice, int chunk,
                     unsigned long long* __restrict__ partials) {
    __shared__ float4 scand[STAGE_N];
    __shared__ unsigned long long skey[4][64][3];

    const int tid   = threadIdx.x;
    const int lane  = tid & 63;
    const int wv    = __builtin_amdgcn_readfirstlane(tid >> 6);
    const int qg    = blockIdx.x / nslice;
    const int slice = blockIdx.x % nslice;
    const int q     = qg * 64 + lane;
    const int qc    = min(q, Nq - 1);

    // cooperative coalesced staging of this block's candidate region
    const int rbeg = slice * 4 * chunk;
    const int rend = min(rbeg + 4 * chunk, Nc);
    int cnt = rend - rbeg;
    if (cnt > STAGE_N) cnt = STAGE_N;   // safety
    for (int i = tid; i < cnt; i += 256) scand[i] = cand[rbeg + i];

    const float4 qp = qry[qc];
    const float  qn = qp.w;
    __syncthreads();

    unsigned long long K0 = ~0ULL, K1 = ~0ULL, K2 = ~0ULL;

    const int jbeg = wv * chunk;
    const int jend = min(jbeg + chunk, cnt);
    #pragma unroll 4
    for (int j = jbeg; j < jend; ++j) {
        const float4 cp = scand[j];          // wave-uniform -> LDS broadcast
        float t   = qn + cp.w;
        float dot = qp.x*cp.x + qp.y*cp.y + qp.z*cp.z;
        float s   = t - 2.0f*dot;            // identical expr to prior rounds
        unsigned int bb = __float_as_uint(s);
        unsigned int u  = bb ^ ((unsigned int)((int)bb >> 31) | 0x80000000u);
        unsigned long long k =
            ((unsigned long long)u << 32) | (unsigned int)(rbeg + j);
        // sorted-insert network: K0<=K1<=K2 stay the 3 smallest keys
        unsigned long long a1 = K1 > k ? K1 : k;
        K2 = K2 < a1 ? K2 : a1;
        unsigned long long a0 = K0 > k ? K0 : k;
        K1 = K1 < a0 ? K1 : a0;
        K0 = K0 < k ? K0 : k;
    }

    skey[wv][lane][0] = K0; skey[wv][lane][1] = K1; skey[wv][lane][2] = K2;
    __syncthreads();

    if (wv == 0 && q < Nq) {
        unsigned long long B0 = K0, B1 = K1, B2 = K2;
        for (int w = 1; w < 4; ++w) {
            ins3k(skey[w][lane][0], B0, B1, B2);
            ins3k(skey[w][lane][1], B0, B1, B2);
            ins3k(skey[w][lane][2], B0, B1, B2);
        }
        unsigned long long* p = partials + ((size_t)q * nslice + slice) * 3;
        p[0] = B0; p[1] = B1; p[2] = B2;
    }
}

// Merge nslice partial top-3 key lists per query; decode indices; weights.
__global__ __launch_bounds__(256)
void knn_finalize_kernel(const unsigned long long* __restrict__ partials,
                         int nslice,
                         const float4* __restrict__ cand, int Nc,
                         const float4* __restrict__ qry, int Nq,
                         int* __restrict__ idx_out, float* __restrict__ wn_out) {
    int q = blockIdx.x * 256 + threadIdx.x;
    if (q >= Nq) return;
    unsigned long long B0 = ~0ULL, B1 = ~0ULL, B2 = ~0ULL;
    const unsigned long long* p = partials + (size_t)q * nslice * 3;
    for (int e = 0; e < nslice * 3; ++e) ins3k(p[e], B0, B1, B2);

    int ix[3];
    ix[0] = (int)(unsigned int)(B0 & 0xffffffffu);
    ix[1] = (int)(unsigned int)(B1 & 0xffffffffu);
    ix[2] = (int)(unsigned int)(B2 & 0xffffffffu);

    const float4 qp = qry[q];
    float w_[3], ws = 0.f;
    for (int k = 0; k < 3; ++k) {
        int ii = min(max(ix[k], 0), Nc - 1);   // clamp: never fault
        ix[k] = ii;
        float4 cp = cand[ii];
        float dx = cp.x - qp.x, dy = cp.y - qp.y, dz = cp.z - qp.z;
        float dd = dx*dx + dy*dy + dz*dz;      // reference diff-form
        w_[k] = 1.0f / fmaxf(dd, EPS_W);
        ws += w_[k];
    }
    float inv = 1.0f / ws;
    for (int k = 0; k < 3; ++k) {
        idx_out[q*3+k] = ix[k];
        wn_out[q*3+k]  = w_[k] * inv;
    }
}

// Fused layernorm + inverse-distance gather -> piv[b,j,c].
template <typename T, typename S>
__device__ void interp_ln_body(const T* __restrict__ xfeat,
                               const T* __restrict__ gamma,
                               const T* __restrict__ beta,
                               const int* __restrict__ idx,
                               const float* __restrict__ wn,
                               S* __restrict__ piv, int Nm, int Np, int C) {
    const int j   = blockIdx.x % Np;
    const int b   = blockIdx.x / Np;
    const int c   = threadIdx.x;
    const int wid = c >> 6;
    const int nw  = C >> 6;

    const float g  = cvt(gamma[c]);
    const float be = cvt(beta[c]);

    __shared__ float red[8];
    float acc = 0.f;
    const float invC = 1.0f / (float)C;

    for (int k = 0; k < 3; ++k) {
        int row = idx[j*3+k];
        row = min(max(row, 0), Nm - 1);
        const T* xp = xfeat + ((size_t)b*Nm + row) * (size_t)C;
        float x = cvt(xp[c]);
        float s = x, s2 = x*x;
        for (int off = 32; off > 0; off >>= 1) {
            s  += __shfl_down(s,  off);
            s2 += __shfl_down(s2, off);
        }
        if ((c & 63) == 0) { red[wid] = s; red[4+wid] = s2; }
        __syncthreads();
        float sum = 0.f, sum2 = 0.f;
        for (int wv = 0; wv < nw; ++wv) { sum += red[wv]; sum2 += red[4+wv]; }
        float mean = sum * invC;
        float var  = sum2 * invC - mean*mean;
        float rs   = rsqrtf(var + EPS_LN);
        acc += wn[j*3+k] * ((x - mean)*rs*g + be);
        __syncthreads();
    }
    S ov; if constexpr (sizeof(S) == 2) ov = __float2bfloat16(acc); else ov = acc;
    piv[((size_t)b*Np + j) * (size_t)C + c] = ov;
}

__global__ __launch_bounds__(128)
void interp_ln_kernel(const void* xfeat, const void* gamma, const void* beta,
                      const int* idx, const float* wn, void* piv,
                      int Nm, int Np, int C, const int* dtype_flag) {
    if (*dtype_flag)
        interp_ln_body<float, float>((const float*)xfeat, (const float*)gamma,
                                     (const float*)beta, idx, wn,
                                     (float*)piv, Nm, Np, C);
    else
        interp_ln_body<__hip_bfloat16, __hip_bfloat16>(
            (const __hip_bfloat16*)xfeat, (const __hip_bfloat16*)gamma,
            (const __hip_bfloat16*)beta, idx, wn,
            (__hip_bfloat16*)piv, Nm, Np, C);
}

// Final gather, 8 channels per thread (uint4 = 8 bf16 / 2x float4).
__global__ __launch_bounds__(256)
void gather_out_kernel(const void* __restrict__ pivv,
                       const int* __restrict__ idx, const float* __restrict__ wn,
                       void* __restrict__ out, int Nm, int Np, int C8,
                       int total8, const int* __restrict__ dtype_flag) {
    int gid = blockIdx.x * 256 + threadIdx.x;
    if (gid >= total8) return;
    int c8 = gid % C8;
    int r  = gid / C8;
    int i  = r % Nm;
    int b  = r / Nm;
    const int C = C8 * 8;
    int jj0 = min(max(idx[i*3+0], 0), Np - 1);
    int jj1 = min(max(idx[i*3+1], 0), Np - 1);
    int jj2 = min(max(idx[i*3+2], 0), Np - 1);
    float w0 = wn[i*3+0], w1 = wn[i*3+1], w2 = wn[i*3+2];

    if (*dtype_flag) {   // fp32 path: fp32 piv, 2x float4 per neighbor row
        const float* pbase = (const float*)pivv + (size_t)b * Np * C;
        const float* p0 = pbase + (size_t)jj0 * C + c8*8;
        const float* p1 = pbase + (size_t)jj1 * C + c8*8;
        const float* p2 = pbase + (size_t)jj2 * C + c8*8;
        float* po = (float*)out + (size_t)gid * 8;
        #pragma unroll
        for (int h = 0; h < 2; ++h) {
            float4 v0 = *(const float4*)(p0 + h*4);
            float4 v1 = *(const float4*)(p1 + h*4);
            float4 v2 = *(const float4*)(p2 + h*4);
            float4 o;
            o.x = w0*v0.x + w1*v1.x + w2*v2.x;
            o.y = w0*v0.y + w1*v1.y + w2*v2.y;
            o.z = w0*v0.z + w1*v1.z + w2*v2.z;
            o.w = w0*v0.w + w1*v1.w + w2*v2.w;
            *(float4*)(po + h*4) = o;
        }
    } else {             // bf16 path: bf16 piv, uint4 = 8 bf16 per neighbor row
        const __hip_bfloat16* pbase = (const __hip_bfloat16*)pivv + (size_t)b * Np * C;
        union U8 { __hip_bfloat16 h[8]; uint4 v; };
        U8 u0, u1, u2, o;
        u0.v = *(const uint4*)(pbase + (size_t)jj0 * C + c8*8);
        u1.v = *(const uint4*)(pbase + (size_t)jj1 * C + c8*8);
        u2.v = *(const uint4*)(pbase + (size_t)jj2 * C + c8*8);
        #pragma unroll
        for (int t = 0; t < 8; ++t) {
            float a = w0*cvt(u0.h[t]) + w1*cvt(u1.h[t]) + w2*cvt(u2.h[t]);
            o.h[t] = __float2bfloat16(a);
        }
        *(((uint4*)out) + gid) = o.v;
    }
}

__global__ void zero_words_kernel(unsigned* out, long long nwords) {
    long long i = (long long)blockIdx.x * 256 + threadIdx.x;
    if (i < nwords) out[i] = 0u;
}

extern "C" void kernel_launch(void* const* d_in, const int* in_sizes, int n_in,
                              void* d_out, int out_size, void* d_ws, size_t ws_size,
                              hipStream_t stream) {
    const int C  = in_sizes[1];
    const int Nm = in_sizes[3] / 3;
    const int Np = in_sizes[4] / 3;
    const int B  = in_sizes[0] / (Nm * C);

    // slicing: each block stages 4*chunk <= STAGE_N candidates
    const int nsl1 = (Nm + 4*STAGE_LIM - 1) / (4*STAGE_LIM);   // piv q over mesh c
    const int chk1 = (Nm + nsl1*4 - 1) / (nsl1*4);
    const int nsl2 = (Np + 4*STAGE_LIM - 1) / (4*STAGE_LIM);   // mesh q over piv c
    const int chk2 = (Np + nsl2*4 - 1) / (nsl2*4);

    size_t off = 0;
    auto carve = [&](size_t bytes) {
        size_t p = off;
        off += (bytes + 255) & ~(size_t)255;
        return p;
    };
    const size_t flag_o  = carve(256);
    const size_t meshs_o = carve((size_t)Nm * sizeof(float4));
    const size_t pivs_o  = carve((size_t)Np * sizeof(float4));
    const size_t piv_o   = carve((size_t)B * Np * C * sizeof(float)); // fp32 worst case
    const size_t i1_o    = carve((size_t)Np * 3 * sizeof(int));
    const size_t w1_o    = carve((size_t)Np * 3 * sizeof(float));
    const size_t i2_o    = carve((size_t)Nm * 3 * sizeof(int));
    const size_t w2_o    = carve((size_t)Nm * 3 * sizeof(float));
    const size_t p1_o    = carve((size_t)Np * nsl1 * 3 * 8);
    const size_t p2_o    = carve((size_t)Nm * nsl2 * 3 * 8);

    if (off > ws_size) {   // never fault; distinct absmax signature
        long long nwords = (long long)out_size / 2;
        zero_words_kernel<<<(int)((nwords + 255) / 256), 256, 0, stream>>>(
            (unsigned*)d_out, nwords);
        return;
    }

    char* base = (char*)d_ws;
    int*    flag   = (int*)   (base + flag_o);
    float4* mesh_s = (float4*)(base + meshs_o);
    float4* piv_s  = (float4*)(base + pivs_o);
    void*   piv    = (void*)  (base + piv_o);
    int*    idx1   = (int*)   (base + i1_o);
    float*  wn1    = (float*) (base + w1_o);
    int*    idx2   = (int*)   (base + i2_o);
    float*  wn2    = (float*) (base + w2_o);
    unsigned long long* part1 = (unsigned long long*)(base + p1_o);
    unsigned long long* part2 = (unsigned long long*)(base + p2_o);

    // 0) stage positions to fp32 float4 (+ dtype detection)
    stage_kernel<<<(Nm + Np + 255) / 256, 256, 0, stream>>>(
        d_in[3], Nm, d_in[4], Np, mesh_s, piv_s, flag);

    // 1) kNN: pivotal queries over mesh candidates
    {
        const int nqg = (Np + 63) / 64;
        knn_scan_kernel<<<nqg * nsl1, 256, 0, stream>>>(
            mesh_s, Nm, piv_s, Np, nsl1, chk1, part1);
        knn_finalize_kernel<<<(Np + 255) / 256, 256, 0, stream>>>(
            part1, nsl1, mesh_s, Nm, piv_s, Np, idx1, wn1);
    }

    // 2) fused layernorm + gather -> piv [B, Np, C]
    interp_ln_kernel<<<B * Np, C, 0, stream>>>(d_in[0], d_in[1], d_in[2],
                                               idx1, wn1, piv, Nm, Np, C, flag);

    // 3) kNN: mesh queries over pivotal candidates
    {
        const int nqg = (Nm + 63) / 64;
        knn_scan_kernel<<<nqg * nsl2, 256, 0, stream>>>(
            piv_s, Np, mesh_s, Nm, nsl2, chk2, part2);
        knn_finalize_kernel<<<(Nm + 255) / 256, 256, 0, stream>>>(
            part2, nsl2, piv_s, Np, mesh_s, Nm, idx2, wn2);
    }

    // 4) gather piv -> out [B*Nm, C], 8 channels/thread
    const int C8 = C / 8;
    const int total8 = B * Nm * C8;
    gather_out_kernel<<<(total8 + 255) / 256, 256, 0, stream>>>(
        piv, idx2, wn2, d_out, Nm, Np, C8, total8, flag);
}